// Round 9
// baseline (498.401 us; speedup 1.0000x reference)
//
#include <hip/hip_runtime.h>

#define NPIX    65536
#define D       64
#define KCODES  1024
#define SPLIT   8
#define KCHUNK  (KCODES / SPLIT)   // 128
#define PIXB    64
#define BLOCK   512
#define XPAD    68                 // row stride in floats

// d_out layout (floats):
//   [0]                  loss
//   [1 .. 4194305)       quantized_out (NCHW, 16x64x64x64)
//   [4194305]            perplexity
//   [4194306 .. 71303170) encodings (65536 x 1024)
//   [71303170 .. 71368706) indices (as float)
#define QUANT_OFF 1
#define PERP_OFF  4194305
#define ENC_OFF   4194306u
#define IDX_OFF   71303170u

// Force a wave-uniform pointer into an SGPR pair so the backend addresses the
// codebook in the scalar domain (s_load / saddr-form loads, no per-load
// v_add_co/v_addc, operands readable directly by v_fma).
__device__ __forceinline__ const float* uniform_ptr(const float* p) {
    uint64_t v = (uint64_t)p;
    uint32_t lo = __builtin_amdgcn_readfirstlane((uint32_t)v);
    uint32_t hi = __builtin_amdgcn_readfirstlane((uint32_t)(v >> 32));
    return (const float*)(((uint64_t)hi << 32) | lo);
}

// numpy pairwise_sum (8 <= n <= 128) for n=64: 8 accumulators over stride-8
// lanes, sequential adds, then ((r0+r1)+(r2+r3))+((r4+r5)+(r6+r7)).
// All ops via __fmul_rn/__fadd_rn so the compiler cannot contract or reorder.

__global__ __launch_bounds__(256) void vq_init(const float* __restrict__ emb,
                                               double* __restrict__ loss_sum,
                                               int* __restrict__ counts,
                                               float* __restrict__ se) {
    int t = blockIdx.x * 256 + threadIdx.x;
    if (t == 0) *loss_sum = 0.0;
    if (t < KCODES) {
        counts[t] = 0;
        const float* e = emb + (size_t)t * D;
        float r[8];
        #pragma unroll
        for (int j = 0; j < 8; ++j) r[j] = __fmul_rn(e[j], e[j]);
        #pragma unroll
        for (int i = 8; i < D; i += 8)
            #pragma unroll
            for (int j = 0; j < 8; ++j)
                r[j] = __fadd_rn(r[j], __fmul_rn(e[i + j], e[i + j]));
        float X = __fadd_rn(__fadd_rn(r[0], r[1]), __fadd_rn(r[2], r[3]));
        float Y = __fadd_rn(__fadd_rn(r[4], r[5]), __fadd_rn(r[6], r[7]));
        se[t] = __fadd_rn(X, Y);
    }
}

// R8 post-mortem: VALU-issue ~125us vs 55us FMA floor, invariant across
// x-path structures -> excess is e-codebook addressing in the divergent
// domain. Fix: SGPR-pair base pointers (uniform_ptr) + drop manual prefetch
// v_movs; rely on compiler lgkmcnt scheduling.
__global__ __launch_bounds__(512) void vq_main(const float* __restrict__ in,
                                               const float* __restrict__ emb,
                                               const float* __restrict__ se,
                                               float* __restrict__ out,
                                               double* __restrict__ loss_sum,
                                               int* __restrict__ counts) {
    __shared__ float xs[PIXB][XPAD];    // 17408 B
    __shared__ float sb[SPLIT][PIXB];
    __shared__ int   sk[SPLIT][PIXB];
    __shared__ int   skfin[PIXB];

    const int tid   = threadIdx.x;
    const int lane  = tid & 63;
    const int split = tid >> 6;         // 0..7
    const int n0    = blockIdx.x * PIXB;
    const int n     = n0 + lane;
    const int b     = n0 >> 12;         // batch (constant per block: 4096%64==0)
    const int s0    = n0 & 4095;

    // stage with transpose: global [d][pixel] (coalesced reads) -> xs[pixel][d]
    {
        const float* base = in + ((size_t)b << 18) + s0;
        #pragma unroll
        for (int i = 0; i < 8; ++i) {
            int d = split + (i << 3);
            xs[lane][d] = base[((size_t)d << 12) + lane];
        }
    }
    __syncthreads();

    // s_x exactly as numpy's pairwise_sum(flat*flat): r[j] += x[8i+j]^2 in
    // ascending i, via ordered quad loads from own row.
    float sx;
    {
        float r[8];
        {
            float4 q0 = *(const float4*)&xs[lane][0];
            float4 q1 = *(const float4*)&xs[lane][4];
            r[0] = __fmul_rn(q0.x, q0.x); r[1] = __fmul_rn(q0.y, q0.y);
            r[2] = __fmul_rn(q0.z, q0.z); r[3] = __fmul_rn(q0.w, q0.w);
            r[4] = __fmul_rn(q1.x, q1.x); r[5] = __fmul_rn(q1.y, q1.y);
            r[6] = __fmul_rn(q1.z, q1.z); r[7] = __fmul_rn(q1.w, q1.w);
        }
        #pragma unroll
        for (int i = 8; i < D; i += 8) {
            float4 q0 = *(const float4*)&xs[lane][i];
            float4 q1 = *(const float4*)&xs[lane][i + 4];
            r[0] = __fadd_rn(r[0], __fmul_rn(q0.x, q0.x));
            r[1] = __fadd_rn(r[1], __fmul_rn(q0.y, q0.y));
            r[2] = __fadd_rn(r[2], __fmul_rn(q0.z, q0.z));
            r[3] = __fadd_rn(r[3], __fmul_rn(q0.w, q0.w));
            r[4] = __fadd_rn(r[4], __fmul_rn(q1.x, q1.x));
            r[5] = __fadd_rn(r[5], __fmul_rn(q1.y, q1.y));
            r[6] = __fadd_rn(r[6], __fmul_rn(q1.z, q1.z));
            r[7] = __fadd_rn(r[7], __fmul_rn(q1.w, q1.w));
        }
        float X = __fadd_rn(__fadd_rn(r[0], r[1]), __fadd_rn(r[2], r[3]));
        float Y = __fadd_rn(__fadd_rn(r[4], r[5]), __fadd_rn(r[6], r[7]));
        sx = __fadd_rn(X, Y);
    }

    // wave-uniform codebook chunk: SGPR-pair bases -> scalar-domain loads
    const int kbase = __builtin_amdgcn_readfirstlane(split * KCHUNK);
    const float* eb = uniform_ptr(emb + (size_t)kbase * D);
    const float* hb = uniform_ptr(se + kbase);

    float best = 3.0e38f;
    int bestk  = 0x7fffffff;
    int xrow   = lane;

    for (int k = 0; k < KCHUNK; k += 8) {
        // redefine xrow each iteration so LICM cannot hoist the 16 b128 reads
        // out of the k-loop (would demand 64 live VGPRs -> remat/spill mess)
        asm volatile("" : "+v"(xrow));
        float a[8];
        #pragma unroll
        for (int c = 0; c < 8; ++c) a[c] = 0.f;
        #pragma unroll
        for (int dq = 0; dq < 16; ++dq) {
            float4 xq = *(const float4*)&xs[xrow][dq << 2];
            #pragma unroll
            for (int c = 0; c < 8; ++c) {
                const float* e = eb + ((k + c) << 6) + (dq << 2);
                // single sequential fmaf chain per code, d ascending (sgemm)
                a[c] = fmaf(xq.x, e[0], a[c]);
                a[c] = fmaf(xq.y, e[1], a[c]);
                a[c] = fmaf(xq.z, e[2], a[c]);
                a[c] = fmaf(xq.w, e[3], a[c]);
            }
        }
        #pragma unroll
        for (int c = 0; c < 8; ++c) {
            // numpy: fl( fl(sx + se_k) - 2*m_k )
            float sv = __fsub_rn(__fadd_rn(sx, hb[k + c]), __fmul_rn(2.0f, a[c]));
            // strict < in ascending k == np.argmin first-min semantics
            if (sv < best) { best = sv; bestk = kbase + k + c; }
        }
    }

    sb[split][lane] = best;
    sk[split][lane] = bestk;
    __syncthreads();

    if (split == 0) {
        // ascending split order + strict < preserves np.argmin first-min
        #pragma unroll
        for (int j = 1; j < SPLIT; ++j) {
            float bj = sb[j][lane];
            int   kj = sk[j][lane];
            if (bj < best) { best = bj; bestk = kj; }
        }
        skfin[lane] = bestk;
        atomicAdd(&counts[bestk], 1);
        out[IDX_OFF + (unsigned)n] = (float)bestk;

        // quantized (NCHW) + per-pixel squared error
        const float* eq = emb + (size_t)bestk * D;
        float* qout = out + QUANT_OFF + ((size_t)b << 18) + s0 + lane;
        float mse = 0.f;
        #pragma unroll
        for (int d = 0; d < D; ++d) {
            float q = eq[d];
            qout[(size_t)d << 12] = q;
            float df = q - xs[lane][d];
            mse = fmaf(df, df, mse);
        }
        #pragma unroll
        for (int off = 32; off; off >>= 1) mse += __shfl_down(mse, off);
        if (lane == 0) atomicAdd(loss_sum, (double)mse);
    }
    __syncthreads();

    // one-hot encodings rows for this block's 64 pixels (256 KB).
    // Region starts at ENC_OFF + n0*1024 (global float idx == 2 mod 4), so
    // shift by 2 floats for aligned float4 stores; head/tail as float2.
    float4* dst4 = (float4*)(out + ENC_OFF + (size_t)n0 * KCODES + 2);
    for (int i = tid; i < 16383; i += BLOCK) {
        int flat = (i << 2) + 2;          // 2 .. 65530
        int r0 = flat >> 10;
        int r1 = (flat + 3) >> 10;        // row crossing only at c==1022
        int k0 = skfin[r0];
        int k1 = skfin[r1];
        int c  = flat & 1023;             // in {2,6,...,1022}
        float4 v;
        v.x = (c == k0) ? 1.f : 0.f;
        v.y = (c + 1 == k0) ? 1.f : 0.f;
        v.z = (((flat + 2) & 1023) == k1) ? 1.f : 0.f;
        v.w = (((flat + 3) & 1023) == k1) ? 1.f : 0.f;
        dst4[i] = v;
    }
    if (tid == 0) {
        float2* dh = (float2*)(out + ENC_OFF + (size_t)n0 * KCODES);
        int kh = skfin[0];
        float2 h2; h2.x = (kh == 0) ? 1.f : 0.f; h2.y = (kh == 1) ? 1.f : 0.f;
        *dh = h2;
        float2* dt = (float2*)(out + ENC_OFF + (size_t)n0 * KCODES + 65534);
        int kt = skfin[63];
        float2 t2; t2.x = (kt == 1022) ? 1.f : 0.f; t2.y = (kt == 1023) ? 1.f : 0.f;
        *dt = t2;
    }
}

__global__ __launch_bounds__(256) void vq_fin(const double* __restrict__ loss_sum,
                                              const int* __restrict__ counts,
                                              float* __restrict__ out) {
    __shared__ double red[256];
    int t = threadIdx.x;
    double ent = 0.0;
    for (int k = t; k < KCODES; k += 256) {
        double p = (double)counts[k] / 65536.0;
        ent -= p * log(p + 1e-10);
    }
    red[t] = ent;
    __syncthreads();
    for (int o = 128; o; o >>= 1) {
        if (t < o) red[t] += red[t + o];
        __syncthreads();
    }
    if (t == 0) {
        out[PERP_OFF] = (float)exp(red[0]);
        out[0] = (float)(1.25 * (*loss_sum) / 4194304.0);
    }
}

extern "C" void kernel_launch(void* const* d_in, const int* in_sizes, int n_in,
                              void* d_out, int out_size, void* d_ws, size_t ws_size,
                              hipStream_t stream) {
    const float* in  = (const float*)d_in[0];
    const float* emb = (const float*)d_in[1];
    float* out = (float*)d_out;

    double* loss_sum = (double*)d_ws;
    int*    counts   = (int*)((char*)d_ws + 8);
    float*  se       = (float*)((char*)d_ws + 8 + 4096);

    vq_init<<<4, 256, 0, stream>>>(emb, loss_sum, counts, se);
    vq_main<<<NPIX / PIXB, BLOCK, 0, stream>>>(in, emb, se, out, loss_sum, counts);
    vq_fin<<<1, 256, 0, stream>>>(loss_sum, counts, out);
}

// Round 10
// 497.969 us; speedup vs baseline: 1.0009x; 1.0009x over previous
//
#include <hip/hip_runtime.h>

#define NPIX    65536
#define D       64
#define KCODES  1024
#define SPLIT   8
#define KCHUNK  (KCODES / SPLIT)   // 128
#define PIXB    64
#define BLOCK   512
#define XPAD    68                 // row stride in floats

// d_out layout (floats):
//   [0]                  loss
//   [1 .. 4194305)       quantized_out (NCHW, 16x64x64x64)
//   [4194305]            perplexity
//   [4194306 .. 71303170) encodings (65536 x 1024)
//   [71303170 .. 71368706) indices (as float)
#define QUANT_OFF 1
#define PERP_OFF  4194305
#define ENC_OFF   4194306u
#define IDX_OFF   71303170u

// numpy pairwise_sum (8 <= n <= 128) for n=64: 8 accumulators over stride-8
// lanes, sequential adds, then ((r0+r1)+(r2+r3))+((r4+r5)+(r6+r7)).
// All ops via __fmul_rn/__fadd_rn so the compiler cannot contract or reorder.

__global__ __launch_bounds__(256) void vq_init(const float* __restrict__ emb,
                                               double* __restrict__ loss_sum,
                                               int* __restrict__ counts,
                                               float* __restrict__ se) {
    int t = blockIdx.x * 256 + threadIdx.x;
    if (t == 0) *loss_sum = 0.0;
    if (t < KCODES) {
        counts[t] = 0;
        const float* e = emb + (size_t)t * D;
        float r[8];
        #pragma unroll
        for (int j = 0; j < 8; ++j) r[j] = __fmul_rn(e[j], e[j]);
        #pragma unroll
        for (int i = 8; i < D; i += 8)
            #pragma unroll
            for (int j = 0; j < 8; ++j)
                r[j] = __fadd_rn(r[j], __fmul_rn(e[i + j], e[i + j]));
        float X = __fadd_rn(__fadd_rn(r[0], r[1]), __fadd_rn(r[2], r[3]));
        float Y = __fadd_rn(__fadd_rn(r[4], r[5]), __fadd_rn(r[6], r[7]));
        se[t] = __fadd_rn(X, Y);
    }
}

// R9 post-mortem: forcing e onto s_load serialized the loop (s_load and
// ds_read share lgkmcnt but complete out-of-order -> every e-use drains all
// x ds_reads; VALUBusy 26%). R5-R8's 60-65% plateau = same cross-drain in
// milder form. Fix: opaque vz VGPR in e/hb addresses -> vector path
// (vmcnt, separate counter), broadcast-coalesced global_load_dwordx4.
__global__ __launch_bounds__(512) void vq_main(const float* __restrict__ in,
                                               const float* __restrict__ emb,
                                               const float* __restrict__ se,
                                               float* __restrict__ out,
                                               double* __restrict__ loss_sum,
                                               int* __restrict__ counts) {
    __shared__ float xs[PIXB][XPAD];    // 17408 B
    __shared__ float sb[SPLIT][PIXB];
    __shared__ int   sk[SPLIT][PIXB];
    __shared__ int   skfin[PIXB];

    const int tid   = threadIdx.x;
    const int lane  = tid & 63;
    const int split = tid >> 6;         // 0..7
    const int n0    = blockIdx.x * PIXB;
    const int n     = n0 + lane;
    const int b     = n0 >> 12;         // batch (constant per block: 4096%64==0)
    const int s0    = n0 & 4095;

    // stage with transpose: global [d][pixel] (coalesced reads) -> xs[pixel][d]
    {
        const float* base = in + ((size_t)b << 18) + s0;
        #pragma unroll
        for (int i = 0; i < 8; ++i) {
            int d = split + (i << 3);
            xs[lane][d] = base[((size_t)d << 12) + lane];
        }
    }
    __syncthreads();

    // s_x exactly as numpy's pairwise_sum(flat*flat): r[j] += x[8i+j]^2 in
    // ascending i, via ordered quad loads from own row.
    float sx;
    {
        float r[8];
        {
            float4 q0 = *(const float4*)&xs[lane][0];
            float4 q1 = *(const float4*)&xs[lane][4];
            r[0] = __fmul_rn(q0.x, q0.x); r[1] = __fmul_rn(q0.y, q0.y);
            r[2] = __fmul_rn(q0.z, q0.z); r[3] = __fmul_rn(q0.w, q0.w);
            r[4] = __fmul_rn(q1.x, q1.x); r[5] = __fmul_rn(q1.y, q1.y);
            r[6] = __fmul_rn(q1.z, q1.z); r[7] = __fmul_rn(q1.w, q1.w);
        }
        #pragma unroll
        for (int i = 8; i < D; i += 8) {
            float4 q0 = *(const float4*)&xs[lane][i];
            float4 q1 = *(const float4*)&xs[lane][i + 4];
            r[0] = __fadd_rn(r[0], __fmul_rn(q0.x, q0.x));
            r[1] = __fadd_rn(r[1], __fmul_rn(q0.y, q0.y));
            r[2] = __fadd_rn(r[2], __fmul_rn(q0.z, q0.z));
            r[3] = __fadd_rn(r[3], __fmul_rn(q0.w, q0.w));
            r[4] = __fadd_rn(r[4], __fmul_rn(q1.x, q1.x));
            r[5] = __fadd_rn(r[5], __fmul_rn(q1.y, q1.y));
            r[6] = __fadd_rn(r[6], __fmul_rn(q1.z, q1.z));
            r[7] = __fadd_rn(r[7], __fmul_rn(q1.w, q1.w));
        }
        float X = __fadd_rn(__fadd_rn(r[0], r[1]), __fadd_rn(r[2], r[3]));
        float Y = __fadd_rn(__fadd_rn(r[4], r[5]), __fadd_rn(r[6], r[7]));
        sx = __fadd_rn(X, Y);
    }

    // wave-uniform codebook chunk base (SGPR) + opaque zero VGPR component:
    // forces saddr+voffset global_load (vmcnt) instead of s_load (lgkmcnt)
    const int kbase = __builtin_amdgcn_readfirstlane(split * KCHUNK);
    const float* eb = emb + (size_t)kbase * D;
    const float* hb = se + kbase;
    int vz = 0;
    asm volatile("" : "+v"(vz));

    float best = 3.0e38f;
    int bestk  = 0x7fffffff;
    int xrow   = lane;

    for (int k = 0; k < KCHUNK; k += 8) {
        // redefine xrow each iteration so LICM cannot hoist the 16 b128 reads
        // out of the k-loop (would demand 64 live VGPRs -> remat/spill mess)
        asm volatile("" : "+v"(xrow));
        float a[8];
        #pragma unroll
        for (int c = 0; c < 8; ++c) a[c] = 0.f;
        float4 xq = *(const float4*)&xs[xrow][0];
        #pragma unroll
        for (int dq = 0; dq < 16; ++dq) {
            // 1-deep prefetch of the next d-quad hides LDS latency under FMAs
            float4 nxt = (dq < 15) ? *(const float4*)&xs[xrow][(dq + 1) << 2] : xq;
            #pragma unroll
            for (int c = 0; c < 8; ++c) {
                const float* e = eb + vz + ((k + c) << 6) + (dq << 2);
                // single sequential fmaf chain per code, d ascending (sgemm)
                a[c] = fmaf(xq.x, e[0], a[c]);
                a[c] = fmaf(xq.y, e[1], a[c]);
                a[c] = fmaf(xq.z, e[2], a[c]);
                a[c] = fmaf(xq.w, e[3], a[c]);
            }
            xq = nxt;
        }
        #pragma unroll
        for (int c = 0; c < 8; ++c) {
            // numpy: fl( fl(sx + se_k) - 2*m_k )
            float hv = hb[vz + k + c];
            float sv = __fsub_rn(__fadd_rn(sx, hv), __fmul_rn(2.0f, a[c]));
            // strict < in ascending k == np.argmin first-min semantics
            if (sv < best) { best = sv; bestk = kbase + k + c; }
        }
    }

    sb[split][lane] = best;
    sk[split][lane] = bestk;
    __syncthreads();

    if (split == 0) {
        // ascending split order + strict < preserves np.argmin first-min
        #pragma unroll
        for (int j = 1; j < SPLIT; ++j) {
            float bj = sb[j][lane];
            int   kj = sk[j][lane];
            if (bj < best) { best = bj; bestk = kj; }
        }
        skfin[lane] = bestk;
        atomicAdd(&counts[bestk], 1);
        out[IDX_OFF + (unsigned)n] = (float)bestk;

        // quantized (NCHW) + per-pixel squared error
        const float* eq = emb + (size_t)bestk * D;
        float* qout = out + QUANT_OFF + ((size_t)b << 18) + s0 + lane;
        float mse = 0.f;
        #pragma unroll
        for (int d = 0; d < D; ++d) {
            float q = eq[d];
            qout[(size_t)d << 12] = q;
            float df = q - xs[lane][d];
            mse = fmaf(df, df, mse);
        }
        #pragma unroll
        for (int off = 32; off; off >>= 1) mse += __shfl_down(mse, off);
        if (lane == 0) atomicAdd(loss_sum, (double)mse);
    }
    __syncthreads();

    // one-hot encodings rows for this block's 64 pixels (256 KB).
    // Region starts at ENC_OFF + n0*1024 (global float idx == 2 mod 4), so
    // shift by 2 floats for aligned float4 stores; head/tail as float2.
    float4* dst4 = (float4*)(out + ENC_OFF + (size_t)n0 * KCODES + 2);
    for (int i = tid; i < 16383; i += BLOCK) {
        int flat = (i << 2) + 2;          // 2 .. 65530
        int r0 = flat >> 10;
        int r1 = (flat + 3) >> 10;        // row crossing only at c==1022
        int k0 = skfin[r0];
        int k1 = skfin[r1];
        int c  = flat & 1023;             // in {2,6,...,1022}
        float4 v;
        v.x = (c == k0) ? 1.f : 0.f;
        v.y = (c + 1 == k0) ? 1.f : 0.f;
        v.z = (((flat + 2) & 1023) == k1) ? 1.f : 0.f;
        v.w = (((flat + 3) & 1023) == k1) ? 1.f : 0.f;
        dst4[i] = v;
    }
    if (tid == 0) {
        float2* dh = (float2*)(out + ENC_OFF + (size_t)n0 * KCODES);
        int kh = skfin[0];
        float2 h2; h2.x = (kh == 0) ? 1.f : 0.f; h2.y = (kh == 1) ? 1.f : 0.f;
        *dh = h2;
        float2* dt = (float2*)(out + ENC_OFF + (size_t)n0 * KCODES + 65534);
        int kt = skfin[63];
        float2 t2; t2.x = (kt == 1022) ? 1.f : 0.f; t2.y = (kt == 1023) ? 1.f : 0.f;
        *dt = t2;
    }
}

__global__ __launch_bounds__(256) void vq_fin(const double* __restrict__ loss_sum,
                                              const int* __restrict__ counts,
                                              float* __restrict__ out) {
    __shared__ double red[256];
    int t = threadIdx.x;
    double ent = 0.0;
    for (int k = t; k < KCODES; k += 256) {
        double p = (double)counts[k] / 65536.0;
        ent -= p * log(p + 1e-10);
    }
    red[t] = ent;
    __syncthreads();
    for (int o = 128; o; o >>= 1) {
        if (t < o) red[t] += red[t + o];
        __syncthreads();
    }
    if (t == 0) {
        out[PERP_OFF] = (float)exp(red[0]);
        out[0] = (float)(1.25 * (*loss_sum) / 4194304.0);
    }
}

extern "C" void kernel_launch(void* const* d_in, const int* in_sizes, int n_in,
                              void* d_out, int out_size, void* d_ws, size_t ws_size,
                              hipStream_t stream) {
    const float* in  = (const float*)d_in[0];
    const float* emb = (const float*)d_in[1];
    float* out = (float*)d_out;

    double* loss_sum = (double*)d_ws;
    int*    counts   = (int*)((char*)d_ws + 8);
    float*  se       = (float*)((char*)d_ws + 8 + 4096);

    vq_init<<<4, 256, 0, stream>>>(emb, loss_sum, counts, se);
    vq_main<<<NPIX / PIXB, BLOCK, 0, stream>>>(in, emb, se, out, loss_sum, counts);
    vq_fin<<<1, 256, 0, stream>>>(loss_sum, counts, out);
}

// Round 11
// 154.442 us; speedup vs baseline: 3.2271x; 3.2243x over previous
//
#include <hip/hip_runtime.h>

#define NPIX    65536
#define D       64
#define KCODES  1024
#define PIXB    64
#define BLOCK   512
#define XPAD    68                 // xs row stride in floats
#define CAP     64                 // per-pixel candidate list capacity
#define GFAC    0.036f             // certified gate factor (2B=0.0316 + slack)

// d_out layout (floats):
//   [0]                  loss
//   [1 .. 4194305)       quantized_out (NCHW, 16x64x64x64)
//   [4194305]            perplexity
//   [4194306 .. 71303170) encodings (65536 x 1024)
//   [71303170 .. 71368706) indices (as float)
#define QUANT_OFF 1
#define PERP_OFF  4194305
#define ENC_OFF   4194306u
#define IDX_OFF   71303170u

typedef float f32x4 __attribute__((ext_vector_type(4)));
typedef short bf16x8 __attribute__((ext_vector_type(8)));

// RNE float->bf16 bits (deterministic, matches hardware RNE)
__device__ __forceinline__ unsigned short f2bf(float f) {
    unsigned u = __float_as_uint(f);
    return (unsigned short)((u + 0x7fffu + ((u >> 16) & 1u)) >> 16);
}
__device__ __forceinline__ bf16x8 pack8(const float* p) {
    bf16x8 v;
    v[0] = (short)f2bf(p[0]); v[1] = (short)f2bf(p[1]);
    v[2] = (short)f2bf(p[2]); v[3] = (short)f2bf(p[3]);
    v[4] = (short)f2bf(p[4]); v[5] = (short)f2bf(p[5]);
    v[6] = (short)f2bf(p[6]); v[7] = (short)f2bf(p[7]);
    return v;
}

// numpy pairwise_sum (n=64): 8 accumulators stride-8, then
// ((r0+r1)+(r2+r3))+((r4+r5)+(r6+r7)); __f*_rn blocks contraction.
__global__ __launch_bounds__(256) void vq_init(const float* __restrict__ emb,
                                               double* __restrict__ loss_sum,
                                               int* __restrict__ counts,
                                               float* __restrict__ se) {
    int t = blockIdx.x * 256 + threadIdx.x;
    if (t == 0) *loss_sum = 0.0;
    if (t < KCODES) {
        counts[t] = 0;
        const float* e = emb + (size_t)t * D;
        float r[8];
        #pragma unroll
        for (int j = 0; j < 8; ++j) r[j] = __fmul_rn(e[j], e[j]);
        #pragma unroll
        for (int i = 8; i < D; i += 8)
            #pragma unroll
            for (int j = 0; j < 8; ++j)
                r[j] = __fadd_rn(r[j], __fmul_rn(e[i + j], e[i + j]));
        float X = __fadd_rn(__fadd_rn(r[0], r[1]), __fadd_rn(r[2], r[3]));
        float Y = __fadd_rn(__fadd_rn(r[4], r[5]), __fadd_rn(r[6], r[7]));
        se[t] = __fadd_rn(X, Y);
    }
}

// MFMA bf16 screen (certified gate) + exact numpy-chain recheck.
// Screen error bound B = 0.0158*||x||*||e||max; gate = gmin + GFAC*sqrt(sx*semaxsq)
// provably contains numpy's fp32 argmin; recheck replicates numpy bit-exactly.
__global__ __launch_bounds__(512) void vq_main(const float* __restrict__ in,
                                               const float* __restrict__ emb,
                                               const float* __restrict__ se,
                                               float* __restrict__ out,
                                               double* __restrict__ loss_sum,
                                               int* __restrict__ counts) {
    __shared__ float xs[PIXB][XPAD];          // 17408 B
    __shared__ float sls[KCODES];             // 4096 B (fp32 se, = numpy fl)
    __shared__ float wmin[8][PIXB];           // per-wave per-pixel screen min
    __shared__ float gate[PIXB];
    __shared__ float sxs[PIXB];
    __shared__ float smx[PIXB];
    __shared__ float semaxsq;
    __shared__ int   cnt[PIXB];
    __shared__ unsigned short list[PIXB][CAP];
    __shared__ int   skfin[PIXB];

    const int tid  = threadIdx.x;
    const int lane = tid & 63;
    const int wid  = tid >> 6;                // 0..7
    const int n0   = blockIdx.x * PIXB;
    const int b    = n0 >> 12;
    const int s0   = n0 & 4095;

    // stage x tile (transpose) + se into LDS
    {
        const float* base = in + ((size_t)b << 18) + s0;
        #pragma unroll
        for (int i = 0; i < 8; ++i) {
            int d = wid + (i << 3);
            xs[lane][d] = base[((size_t)d << 12) + lane];
        }
        sls[tid] = se[tid];
        sls[tid + 512] = se[tid + 512];
    }
    __syncthreads();

    // tid<64: exact numpy pairwise sx per pixel + partial max of se
    if (tid < PIXB) {
        float r[8];
        #pragma unroll
        for (int j = 0; j < 8; ++j) {
            float v = xs[tid][j];
            r[j] = __fmul_rn(v, v);
        }
        #pragma unroll
        for (int i = 8; i < D; i += 8)
            #pragma unroll
            for (int j = 0; j < 8; ++j) {
                float v = xs[tid][i + j];
                r[j] = __fadd_rn(r[j], __fmul_rn(v, v));
            }
        float X = __fadd_rn(__fadd_rn(r[0], r[1]), __fadd_rn(r[2], r[3]));
        float Y = __fadd_rn(__fadd_rn(r[4], r[5]), __fadd_rn(r[6], r[7]));
        sxs[tid] = __fadd_rn(X, Y);
        float mx = sls[tid << 4];
        #pragma unroll
        for (int j = 1; j < 16; ++j) mx = fmaxf(mx, sls[(tid << 4) + j]);
        smx[tid] = mx;
    }

    const int wbase = wid * 128;
    const int arow  = lane & 15;              // A row / B col within tile
    const int kgrp  = (lane >> 4) << 3;       // k-offset of this lane's 8 elems
    const int rbase = (lane >> 4) << 2;       // D row base

    // ---------------- P1: screen, per-wave per-pixel min ----------------
    float mreg[4][4];
    #pragma unroll
    for (int pt = 0; pt < 4; ++pt)
        #pragma unroll
        for (int r = 0; r < 4; ++r) mreg[pt][r] = 3.0e38f;

    #pragma unroll
    for (int s = 0; s < 2; ++s) {
        const int cbase = wbase + s * 64;
        f32x4 acc[4][4];
        #pragma unroll
        for (int pt = 0; pt < 4; ++pt)
            #pragma unroll
            for (int kt = 0; kt < 4; ++kt) acc[pt][kt] = (f32x4){0.f, 0.f, 0.f, 0.f};
        #pragma unroll
        for (int ks = 0; ks < 2; ++ks) {
            bf16x8 af[4];
            #pragma unroll
            for (int pt = 0; pt < 4; ++pt)
                af[pt] = pack8(&xs[pt * 16 + arow][ks * 32 + kgrp]);
            #pragma unroll
            for (int kt = 0; kt < 4; ++kt) {
                int code = cbase + kt * 16 + arow;
                bf16x8 bf_ = pack8(emb + ((size_t)code << 6) + ks * 32 + kgrp);
                #pragma unroll
                for (int pt = 0; pt < 4; ++pt)
                    acc[pt][kt] = __builtin_amdgcn_mfma_f32_16x16x32_bf16(
                        af[pt], bf_, acc[pt][kt], 0, 0, 0);
            }
        }
        #pragma unroll
        for (int pt = 0; pt < 4; ++pt)
            #pragma unroll
            for (int kt = 0; kt < 4; ++kt) {
                int code = cbase + kt * 16 + arow;
                #pragma unroll
                for (int r = 0; r < 4; ++r) {
                    float sv = __fsub_rn(sls[code], __fmul_rn(2.0f, acc[pt][kt][r]));
                    mreg[pt][r] = fminf(mreg[pt][r], sv);
                }
            }
    }
    #pragma unroll
    for (int m = 1; m < 16; m <<= 1)
        #pragma unroll
        for (int pt = 0; pt < 4; ++pt)
            #pragma unroll
            for (int r = 0; r < 4; ++r)
                mreg[pt][r] = fminf(mreg[pt][r], __shfl_xor(mreg[pt][r], m));
    if (arow == 0) {
        #pragma unroll
        for (int pt = 0; pt < 4; ++pt)
            #pragma unroll
            for (int r = 0; r < 4; ++r)
                wmin[wid][pt * 16 + rbase + r] = mreg[pt][r];
    }
    __syncthreads();

    if (tid == 0) {
        float mx = smx[0];
        #pragma unroll
        for (int j = 1; j < PIXB; ++j) mx = fmaxf(mx, smx[j]);
        semaxsq = mx;
    }
    __syncthreads();

    if (tid < PIXB) {
        float gm = wmin[0][tid];
        #pragma unroll
        for (int w = 1; w < 8; ++w) gm = fminf(gm, wmin[w][tid]);
        gate[tid] = gm + GFAC * sqrtf(sxs[tid] * semaxsq);
        cnt[tid] = 0;
    }
    __syncthreads();

    // ---------------- P2: recompute screen, append gated candidates -----
    #pragma unroll
    for (int s = 0; s < 2; ++s) {
        const int cbase = wbase + s * 64;
        f32x4 acc[4][4];
        #pragma unroll
        for (int pt = 0; pt < 4; ++pt)
            #pragma unroll
            for (int kt = 0; kt < 4; ++kt) acc[pt][kt] = (f32x4){0.f, 0.f, 0.f, 0.f};
        #pragma unroll
        for (int ks = 0; ks < 2; ++ks) {
            bf16x8 af[4];
            #pragma unroll
            for (int pt = 0; pt < 4; ++pt)
                af[pt] = pack8(&xs[pt * 16 + arow][ks * 32 + kgrp]);
            #pragma unroll
            for (int kt = 0; kt < 4; ++kt) {
                int code = cbase + kt * 16 + arow;
                bf16x8 bf_ = pack8(emb + ((size_t)code << 6) + ks * 32 + kgrp);
                #pragma unroll
                for (int pt = 0; pt < 4; ++pt)
                    acc[pt][kt] = __builtin_amdgcn_mfma_f32_16x16x32_bf16(
                        af[pt], bf_, acc[pt][kt], 0, 0, 0);
            }
        }
        #pragma unroll
        for (int pt = 0; pt < 4; ++pt)
            #pragma unroll
            for (int kt = 0; kt < 4; ++kt) {
                int code = cbase + kt * 16 + arow;
                #pragma unroll
                for (int r = 0; r < 4; ++r) {
                    float sv = __fsub_rn(sls[code], __fmul_rn(2.0f, acc[pt][kt][r]));
                    int px = pt * 16 + rbase + r;
                    if (sv <= gate[px]) {
                        int slot = atomicAdd(&cnt[px], 1);
                        if (slot < CAP) list[px][slot] = (unsigned short)code;
                    }
                }
            }
    }
    __syncthreads();

    // ---------------- P3: exact numpy-chain recheck over gated set ------
    {
        const int px = tid >> 3, c0 = tid & 7;
        const int cn = cnt[px];
        float bv = 3.0e38f;
        int   bk = 0x7fffffff;
        if (cn > CAP) {
            // overflow fallback: exact full scan (correctness-preserving)
            for (int k = c0; k < KCODES; k += 8) {
                const float* er = emb + ((size_t)k << 6);
                float m = 0.f;
                #pragma unroll
                for (int d = 0; d < D; ++d) m = fmaf(xs[px][d], er[d], m);
                float sv = __fsub_rn(__fadd_rn(sxs[px], sls[k]), __fmul_rn(2.0f, m));
                if (sv < bv || (sv == bv && k < bk)) { bv = sv; bk = k; }
            }
        } else {
            for (int i = c0; i < cn; i += 8) {
                int k = list[px][i];
                const float* er = emb + ((size_t)k << 6);
                float m = 0.f;
                #pragma unroll
                for (int d = 0; d < D; ++d) m = fmaf(xs[px][d], er[d], m);
                float sv = __fsub_rn(__fadd_rn(sxs[px], sls[k]), __fmul_rn(2.0f, m));
                if (sv < bv || (sv == bv && k < bk)) { bv = sv; bk = k; }
            }
        }
        #pragma unroll
        for (int m = 4; m; m >>= 1) {
            float ov = __shfl_xor(bv, m);
            int   ok = __shfl_xor(bk, m);
            if (ov < bv || (ov == bv && ok < bk)) { bv = ov; bk = ok; }
        }
        if (c0 == 0) {
            skfin[px] = bk;
            atomicAdd(&counts[bk], 1);
            out[IDX_OFF + (unsigned)(n0 + px)] = (float)bk;
        }
    }
    __syncthreads();

    // ---------------- epilogue (identical numerics to R8) ---------------
    if (tid < PIXB) {
        int bk2 = skfin[tid];
        const float* eq = emb + ((size_t)bk2 << 6);
        float* qout = out + QUANT_OFF + ((size_t)b << 18) + s0 + tid;
        float mse = 0.f;
        #pragma unroll
        for (int d = 0; d < D; ++d) {
            float q = eq[d];
            qout[(size_t)d << 12] = q;
            float df = q - xs[tid][d];
            mse = fmaf(df, df, mse);
        }
        #pragma unroll
        for (int off = 32; off; off >>= 1) mse += __shfl_down(mse, off);
        if (tid == 0) atomicAdd(loss_sum, (double)mse);
    }

    // one-hot encodings (256 KB): aligned float4 body + float2 head/tail
    float4* dst4 = (float4*)(out + ENC_OFF + (size_t)n0 * KCODES + 2);
    for (int i = tid; i < 16383; i += BLOCK) {
        int flat = (i << 2) + 2;
        int r0 = flat >> 10;
        int r1 = (flat + 3) >> 10;
        int k0 = skfin[r0];
        int k1 = skfin[r1];
        int c  = flat & 1023;
        float4 v;
        v.x = (c == k0) ? 1.f : 0.f;
        v.y = (c + 1 == k0) ? 1.f : 0.f;
        v.z = (((flat + 2) & 1023) == k1) ? 1.f : 0.f;
        v.w = (((flat + 3) & 1023) == k1) ? 1.f : 0.f;
        dst4[i] = v;
    }
    if (tid == 0) {
        float2* dh = (float2*)(out + ENC_OFF + (size_t)n0 * KCODES);
        int kh = skfin[0];
        float2 h2; h2.x = (kh == 0) ? 1.f : 0.f; h2.y = (kh == 1) ? 1.f : 0.f;
        *dh = h2;
        float2* dt = (float2*)(out + ENC_OFF + (size_t)n0 * KCODES + 65534);
        int kt = skfin[63];
        float2 t2; t2.x = (kt == 1022) ? 1.f : 0.f; t2.y = (kt == 1023) ? 1.f : 0.f;
        *dt = t2;
    }
}

__global__ __launch_bounds__(256) void vq_fin(const double* __restrict__ loss_sum,
                                              const int* __restrict__ counts,
                                              float* __restrict__ out) {
    __shared__ double red[256];
    int t = threadIdx.x;
    double ent = 0.0;
    for (int k = t; k < KCODES; k += 256) {
        double p = (double)counts[k] / 65536.0;
        ent -= p * log(p + 1e-10);
    }
    red[t] = ent;
    __syncthreads();
    for (int o = 128; o; o >>= 1) {
        if (t < o) red[t] += red[t + o];
        __syncthreads();
    }
    if (t == 0) {
        out[PERP_OFF] = (float)exp(red[0]);
        out[0] = (float)(1.25 * (*loss_sum) / 4194304.0);
    }
}

extern "C" void kernel_launch(void* const* d_in, const int* in_sizes, int n_in,
                              void* d_out, int out_size, void* d_ws, size_t ws_size,
                              hipStream_t stream) {
    const float* in  = (const float*)d_in[0];
    const float* emb = (const float*)d_in[1];
    float* out = (float*)d_out;

    double* loss_sum = (double*)d_ws;
    int*    counts   = (int*)((char*)d_ws + 8);
    float*  se       = (float*)((char*)d_ws + 8 + 4096);

    vq_init<<<4, 256, 0, stream>>>(emb, loss_sum, counts, se);
    vq_main<<<NPIX / PIXB, BLOCK, 0, stream>>>(in, emb, se, out, loss_sum, counts);
    vq_fin<<<1, 256, 0, stream>>>(loss_sum, counts, out);
}